// Round 10
// baseline (150.199 us; speedup 1.0000x reference)
//
#include <hip/hip_runtime.h>
#include <hip/hip_bf16.h>
#include <math.h>

#define BS   32
#define IC   64
#define OC   64
#define HH   128
#define WW   128
#define BANK 256
#define ADDR 64
#define WELEM (OC*IC*9)
#define PLANE (HH*WW)

typedef short short8 __attribute__((ext_vector_type(8)));
typedef float f32x16 __attribute__((ext_vector_type(16)));

__device__ __forceinline__ short f2bf(float f) {
    unsigned u = __builtin_bit_cast(unsigned, f);
    unsigned r = (u + 0x7FFFu + ((u >> 16) & 1u)) >> 16;
    return (short)r;
}

// ---------------- kernel 1: sel_w = softmax(w_addr @ aspace^T) --------------
__global__ __launch_bounds__(BANK) void k_selw(const float* __restrict__ w_addr,
                                               const float* __restrict__ aspace,
                                               float* __restrict__ sel_w) {
    int b = blockIdx.x;
    int n = threadIdx.x;
    const float* wa = w_addr + b * ADDR;
    const float* as = aspace + n * ADDR;
    float dot = 0.f;
#pragma unroll
    for (int k = 0; k < ADDR; ++k) dot = fmaf(wa[k], as[k], dot);

    __shared__ float red[BANK];
    red[n] = dot; __syncthreads();
    for (int s = BANK / 2; s > 0; s >>= 1) {
        if (n < s) red[n] = fmaxf(red[n], red[n + s]);
        __syncthreads();
    }
    float m = red[0]; __syncthreads();
    float e = expf(dot - m);
    red[n] = e; __syncthreads();
    for (int s = BANK / 2; s > 0; s >>= 1) {
        if (n < s) red[n] += red[n + s];
        __syncthreads();
    }
    sel_w[b * BANK + n] = e / red[0];
}

// ---------------- kernel 2: bias[b][o] = softmax(b_addr@aspace^T) @ b_bank --
__global__ __launch_bounds__(BANK) void k_bias(const float* __restrict__ b_addr,
                                               const float* __restrict__ aspace,
                                               const float* __restrict__ b_bank,
                                               float* __restrict__ bias) {
    int bo = blockIdx.x;
    int n  = threadIdx.x;
    const float* ba = b_addr + (size_t)bo * ADDR;
    const float* as = aspace + n * ADDR;
    float dot = 0.f;
#pragma unroll
    for (int k = 0; k < ADDR; ++k) dot = fmaf(ba[k], as[k], dot);

    __shared__ float red[BANK];
    red[n] = dot; __syncthreads();
    for (int s = BANK / 2; s > 0; s >>= 1) {
        if (n < s) red[n] = fmaxf(red[n], red[n + s]);
        __syncthreads();
    }
    float m = red[0]; __syncthreads();
    float e = expf(dot - m);
    red[n] = e; __syncthreads();
    for (int s = BANK / 2; s > 0; s >>= 1) {
        if (n < s) red[n] += red[n + s];
        __syncthreads();
    }
    float denom = red[0]; __syncthreads();
    red[n] = e * b_bank[n]; __syncthreads();
    for (int s = BANK / 2; s > 0; s >>= 1) {
        if (n < s) red[n] += red[n + s];
        __syncthreads();
    }
    if (n == 0) bias[bo] = red[0] / denom;
}

// ---------------- kernel 3: weight mix -> bf16, MFMA-fragment layout --------
// wmb[b][tap(9)][icg(8)][oc(64)][ic8(8)]  (bf16)
__global__ __launch_bounds__(256) void k_wmix(const float* __restrict__ sel_w,
                                              const float* __restrict__ w_bank,
                                              __hip_bfloat16* __restrict__ wmb) {
    __shared__ float s_red[4 * 32 * 64];   // [chunk][b][jl] = 32 KB

    int tid = threadIdx.x;
    int jl  = tid & 63;
    int c   = tid >> 6;
    int jb  = blockIdx.x * 64 + jl;

    int n0 = __builtin_amdgcn_readfirstlane(c * 64);
    const float* selp = sel_w + n0;

    float wv[64];
#pragma unroll
    for (int n = 0; n < 64; ++n)
        wv[n] = w_bank[(size_t)(n0 + n) * WELEM + jb];

    float acc[BS];
#pragma unroll
    for (int b = 0; b < BS; ++b) acc[b] = 0.f;
#pragma unroll
    for (int b = 0; b < BS; ++b)
#pragma unroll
        for (int n = 0; n < 64; ++n)
            acc[b] = fmaf(selp[b * BANK + n], wv[n], acc[b]);

#pragma unroll
    for (int b = 0; b < BS; ++b)
        s_red[(c * 32 + b) * 64 + jl] = acc[b];
    __syncthreads();

    int B0  = (tid * 8) & 31;
    int jl2 = (tid * 8) >> 5;
    int j   = blockIdx.x * 64 + jl2;
    int o   = j / 576;
    int rem = j - o * 576;
    int i   = rem / 9;
    int tap = rem - i * 9;
    size_t base = ((size_t)tap * 8 + (i >> 3)) * 512 + (size_t)o * 8 + (i & 7);
#pragma unroll
    for (int u = 0; u < 8; ++u) {
        int b = B0 + u;
        float v = s_red[(0 * 32 + b) * 64 + jl2] + s_red[(1 * 32 + b) * 64 + jl2]
                + s_red[(2 * 32 + b) * 64 + jl2] + s_red[(3 * 32 + b) * 64 + jl2];
        short sv = f2bf(v);
        wmb[(size_t)b * (9 * 8 * 64 * 8) + base] = *reinterpret_cast<__hip_bfloat16*>(&sv);
    }
}

// ---------------- kernel 4: FUSED implicit-GEMM conv (reads fp32 NCHW) ------
// 4096 blocks = (b, 64 strips of 2 rows, 2 col-halves), XCD-swizzled.
// 256 thr / 4 waves; wave = (row wr, oc-half oh): 32 oc x 64 px, 2 acc tiles.
// w-fragments live in REGISTERS (9 coalesced b128 loads/chunk from L2-resident
// wmb) -> LDS holds only x (8.5 KB) -> 4 independent blocks/CU; cross-block
// TLP hides load latency (no intra-wave pipelining needed).
__global__ __launch_bounds__(256, 4) void k_conv(const float* __restrict__ x,
                                                 const short* __restrict__ wmb,
                                                 const float* __restrict__ bias,
                                                 float* __restrict__ out) {
    __shared__ short s_x[4 * 2 * 66 * 8];   // [ky4][g2][col66][ic8] = 8448 B
    __shared__ float s_bias[OC];

    int orig    = blockIdx.x;
    int logical = (orig & 7) * 512 + (orig >> 3);   // bijective (4096%8==0)
    int b    = logical >> 7;
    int rem  = logical & 127;
    int y0   = (rem >> 1) * 2;
    int ch   = rem & 1;
    int tid  = threadIdx.x;
    int lane = tid & 63;
    int wv   = tid >> 6;          // 4 waves
    int h    = lane >> 5;
    int ln   = lane & 31;
    int wr   = wv & 1;            // output row within strip
    int oh   = wv >> 1;           // oc half

    if (tid < OC) s_bias[tid] = bias[b * OC + tid];

    const float* xb   = x + (size_t)b * IC * PLANE;
    const short* wmbs = wmb + (size_t)b * 36864;

    // ---- x staging descriptors: 528 units = (ky4)(g2)(cx66); 16B each ----
    // unit u -> ky=u/132, r=u%132, g=r/66, cx=r%66; gy=y0-1+ky, gx=ch*64-1+cx
    int x_goff[3], x_lds[3], x_g[3]; bool x_ok[3];
#pragma unroll
    for (int k = 0; k < 3; ++k) {
        int u = k * 256 + tid;
        bool val = (u < 528);
        int uu = val ? u : 0;
        int ky = uu / 132;
        int r  = uu - ky * 132;
        int g  = r / 66;
        int cx = r - g * 66;
        int gy = y0 - 1 + ky;
        int gx = ch * 64 - 1 + cx;
        x_ok[k]   = val && ((unsigned)gy < (unsigned)HH) && ((unsigned)gx < (unsigned)WW);
        x_g[k]    = g;
        x_goff[k] = gy * WW + gx;
        x_lds[k]  = val ? ((ky * 2 + g) * 66 + cx) * 8 : (528 * 8); // dummy-safe? no:
        // (u>=528 threads masked below; lds index unused when !val)
        if (!val) x_lds[k] = 0;
        if (!val) x_ok[k] = false;
    }
    bool x_val[3];
#pragma unroll
    for (int k = 0; k < 3; ++k) x_val[k] = (k * 256 + tid) < 528;

    f32x16 acc[2];
    acc[0] = (f32x16)0.0f;
    acc[1] = (f32x16)0.0f;

    const short8* sx8 = (const short8*)s_x;

    for (int cc = 0; cc < 4; ++cc) {
        // ---- w-fragments -> registers: 9 coalesced b128 loads (L2-hit) ----
        short8 areg[9];
#pragma unroll
        for (int tap = 0; tap < 9; ++tap)
            areg[tap] = *(const short8*)(wmbs +
                (size_t)((tap * 8 + 2 * cc + h) * 64 + oh * 32 + ln) * 8);

        // ---- x chunk -> LDS (global->reg->pack->ds_write_b128) ----
        float xr[3][8];
#pragma unroll
        for (int k = 0; k < 3; ++k) {
            if (x_ok[k]) {
                const float* p = xb + (size_t)(cc * 16 + x_g[k] * 8) * PLANE + x_goff[k];
#pragma unroll
                for (int e = 0; e < 8; ++e) xr[k][e] = p[(size_t)e * PLANE];
            } else {
#pragma unroll
                for (int e = 0; e < 8; ++e) xr[k][e] = 0.f;
            }
        }
        if (cc) __syncthreads();          // readers of previous chunk done
#pragma unroll
        for (int k = 0; k < 3; ++k) {
            if (x_val[k]) {
                short8 s;
#pragma unroll
                for (int e = 0; e < 8; ++e) s[e] = f2bf(xr[k][e]);
                *(short8*)&s_x[x_lds[k]] = s;
            }
        }
        __syncthreads();

        // ---- 18 MFMA: 9 taps x 2 n-tiles ----
#pragma unroll
        for (int ky = 0; ky < 3; ++ky) {
#pragma unroll
            for (int kx = 0; kx < 3; ++kx) {
                short8 a = areg[ky * 3 + kx];
#pragma unroll
                for (int nt = 0; nt < 2; ++nt) {
                    short8 bb = sx8[((wr + ky) * 2 + h) * 66 + nt * 32 + ln + kx];
                    acc[nt] = __builtin_amdgcn_mfma_f32_32x32x16_bf16(a, bb, acc[nt], 0, 0, 0);
                }
            }
        }
    }

    // epilogue: C/D layout col=lane&31, row=(r&3)+8*(r>>2)+4*h
    int y = y0 + wr;
    float* ob = out + (size_t)b * OC * PLANE;
#pragma unroll
    for (int nt = 0; nt < 2; ++nt) {
#pragma unroll
        for (int r = 0; r < 16; ++r) {
            int oc = oh * 32 + (r & 3) + 8 * (r >> 2) + 4 * h;
            int px = ch * 64 + nt * 32 + ln;
            ob[((size_t)oc * HH + y) * WW + px] = acc[nt][r] + s_bias[oc];
        }
    }
}

// ---------------------------------------------------------------------------
extern "C" void kernel_launch(void* const* d_in, const int* in_sizes, int n_in,
                              void* d_out, int out_size, void* d_ws, size_t ws_size,
                              hipStream_t stream) {
    const float* x      = (const float*)d_in[0];
    const float* w_addr = (const float*)d_in[1];
    const float* b_addr = (const float*)d_in[2];
    const float* w_bank = (const float*)d_in[3];
    const float* b_bank = (const float*)d_in[4];
    const float* aspace = (const float*)d_in[5];
    float* out = (float*)d_out;

    char* ws = (char*)d_ws;
    float*          sel_w = (float*)ws;                     // 32768 B
    float*          bias  = (float*)(ws + 32768);           //  8192 B
    __hip_bfloat16* wmb   = (__hip_bfloat16*)(ws + 40960);  // 2359296 B

    k_selw<<<BS, BANK, 0, stream>>>(w_addr, aspace, sel_w);
    k_bias<<<BS * OC, BANK, 0, stream>>>(b_addr, aspace, b_bank, bias);
    k_wmix<<<WELEM / 64, 256, 0, stream>>>(sel_w, w_bank, wmb);
    k_conv<<<BS * 64 * 2, 256, 0, stream>>>(x, (const short*)wmb, bias, out);
}